// Round 16
// baseline (287.800 us; speedup 1.0000x reference)
//
#include <hip/hip_runtime.h>
#include <hip/hip_bf16.h>
#include <math.h>

typedef __attribute__((ext_vector_type(4))) short short4v;
typedef __attribute__((ext_vector_type(8))) short short8;
typedef __attribute__((ext_vector_type(4))) float f32x4;
typedef __attribute__((ext_vector_type(2))) float f32x2;
typedef _Float16 half8 __attribute__((ext_vector_type(8)));

#define BATCH   4096
#define XLEN    1008
#define NOC1    128
#define NPOS    32
#define NOC2    256
#define NQ      9
#define NCAPS   288
#define NDIM    8

// ws layout (bytes)
#define BWH_OFF   0           // wavelet B-pack fp16, 128 KB
#define BPH_OFF   131072      // conv2 B-pack fp16, 1 MB
#define H2_OFF    1179648     // h2 fp16 [b][pos32][ic128], 33.55 MB
#define U_OFF     34734080    // u fp32 [b][288][8], 37.75 MB

static __device__ __forceinline__ short f2h(float v) {
    _Float16 h = (_Float16)v;
    return *reinterpret_cast<short*>(&h);
}

// packed fp32 fma on batch-pairs: a (splat) * b + c  ->  v_pk_fma_f32
static __device__ __forceinline__ f32x2 pkfma(float a, f32x2 b, f32x2 c) {
    f32x2 av = {a, a};
    return av * b + c;
}

// DPP 16-lane (row) sum — VALU pipe. Bitwise == shfl_xor 1/2/4/8 tree.
template <int CTRL>
static __device__ __forceinline__ float dpp_addf(float x) {
    int y = __builtin_amdgcn_update_dpp(0, __builtin_bit_cast(int, x),
                                        CTRL, 0xf, 0xf, true);
    return x + __builtin_bit_cast(float, y);
}
static __device__ __forceinline__ float rowsum16(float x) {
    x = dpp_addf<0xB1>(x);    // quad_perm xor1
    x = dpp_addf<0x4E>(x);    // quad_perm xor2
    x = dpp_addf<0x141>(x);   // row_half_mirror
    x = dpp_addf<0x140>(x);   // row_mirror
    return x;
}

// ---------------- K1: fused weight packing (wavelet + conv2), fp16 ---------
__global__ __launch_bounds__(256) void k_pack(const float* __restrict__ a,
                                              const float* __restrict__ w,
                                              const float* __restrict__ cw,
                                              short* __restrict__ bwh,
                                              short* __restrict__ bph) {
    int bid = blockIdx.x;
    int tid = threadIdx.x;
    if (bid < 256) {
        int idx = bid * 256 + tid;            // 65536 wavelet elems
        int e    = idx & 7;
        int lane = (idx >> 3) & 63;
        int s    = (idx >> 9) & 15;
        int nt   = idx >> 13;
        int oc = nt * 16 + (lane & 15);
        int k  = s * 32 + (lane >> 4) * 8 + e;
        float t  = -1.0f + 2.0f * (float)k / 511.0f;
        float av = fmaxf(a[oc], 1e-5f);
        float ts = t / av;
        bwh[idx] = f2h(cosf(w[oc] * t) * expf(-0.5f * ts * ts));
    } else {
        int o = (bid - 256) * 256 + tid;      // 524288 conv2 elems
        int e    = o & 7;
        int lane = (o >> 3) & 63;
        int s    = (o >> 9) & 63;
        int nt   = o >> 15;
        int n  = nt * 16 + (lane & 15);
        int j  = lane >> 4;
        int kk = s >> 2;
        int ic = (s & 3) * 32 + j * 8 + e;
        bph[o] = f2h(cw[(n * NOC1 + ic) * 16 + kk]);
    }
}

// ---------------- K2: WavConv via single fp16 MFMA, occupancy-tuned --------
// Block: 4 batches, 256 threads (4 waves), 4 blocks/CU (launch_bounds(256,4)).
// Wave w owns m-tiles {2w, 2w+1} (batch w's two pos-halves), all 8 n-tiles.
// acc = 2x8 f32x4 = 64 VGPR -> ~120 total, 4 waves/SIMD for latency hiding.
// Per-output K-order identical to previous version -> bit-identical h2.
__global__ __launch_bounds__(256, 4) void k_wavconv_mfma(
        const float* __restrict__ x,
        const short* __restrict__ bwh,
        short* __restrict__ h2) {
    __shared__ short xl[4][1512];   // 12096 B; slot(i) = i + 8*(i>>4)

    int tid = threadIdx.x;
    int b0  = blockIdx.x * 4;

    for (int i4 = tid; i4 < 1008; i4 += 256) {
        int b  = i4 / 252;
        int e4 = i4 - b * 252;
        float4 v = *(const float4*)(x + (size_t)(b0 + b) * XLEN + e4 * 4);
        int i    = e4 * 4;
        int slot = i + 8 * (i >> 4);
        short4v hv;
        hv.x = f2h(v.x); hv.y = f2h(v.y); hv.z = f2h(v.z); hv.w = f2h(v.w);
        *(short4v*)&xl[b][slot] = hv;
    }
    __syncthreads();

    int lane = tid & 63;
    int w    = tid >> 6;     // 0..3 == block-local batch
    int col  = lane & 15;
    int rg   = lane >> 4;    // 0..3

    f32x4 acc[2][8];
    f32x4 z = {0.f, 0.f, 0.f, 0.f};
#pragma unroll
    for (int tl = 0; tl < 2; ++tl)
#pragma unroll
        for (int nt = 0; nt < 8; ++nt) acc[tl][nt] = z;

    for (int s = 0; s < 16; ++s) {
        half8 Bh[8];
#pragma unroll
        for (int nt = 0; nt < 8; ++nt) {
            size_t off = ((size_t)(nt * 16 + s) * 64 + lane) * 8;
            Bh[nt] = __builtin_bit_cast(half8, *(const short8*)(bwh + off));
        }
#pragma unroll
        for (int tl = 0; tl < 2; ++tl) {
            int pos = tl * 16 + col;
            int i    = (pos + 2 * s) * 16 + rg * 8;
            int slot = i + 8 * (i >> 4);
            half8 ah = __builtin_bit_cast(half8, *(const short8*)&xl[w][slot]);
#pragma unroll
            for (int nt = 0; nt < 8; ++nt)
                acc[tl][nt] = __builtin_amdgcn_mfma_f32_16x16x32_f16(ah, Bh[nt], acc[tl][nt], 0, 0, 0);
        }
    }

    // Epilogue: C/D layout col=lane&15 (oc), row=rg*4+r (pos).
    int b = b0 + w;
#pragma unroll
    for (int tl = 0; tl < 2; ++tl) {
        int ph = tl * 16;
#pragma unroll
        for (int nt = 0; nt < 8; ++nt) {
            int oc = nt * 16 + col;
#pragma unroll
            for (int r = 0; r < 4; ++r) {
                int pos = ph + rg * 4 + r;
                h2[((size_t)b * NPOS + pos) * NOC1 + oc] = f2h(acc[tl][nt][r]);
            }
        }
    }
}

// ---------------- K3: PrimaryCaps conv, full-N, fp16 MFMA + squash ---------
__global__ __launch_bounds__(512, 4) void k_conv_mfma(const short* __restrict__ h2,
                                                      const short* __restrict__ bph,
                                                      const float* __restrict__ cb,
                                                      float* __restrict__ u) {
    __shared__ char smem[36864];         // 2 A-buffers (6400 B each); p_lds epilogue
    short* A0 = (short*)smem;            // [80 rows][stride 40]
    short* A1 = (short*)(smem + 6400);
    float* p_lds = (float*)smem;         // [8 b][1152]

    int tid  = threadIdx.x;
    int w    = tid >> 6;
    int lane = tid & 63;
    int col  = lane & 15;
    int rg   = lane >> 4;
    int b0   = blockIdx.x * 8;

    f32x4 acc[5][2];
    f32x4 z = {0.f, 0.f, 0.f, 0.f};
#pragma unroll
    for (int mt = 0; mt < 5; ++mt) { acc[mt][0] = z; acc[mt][1] = z; }

    auto stageA = [&](int s, short* dst) {
        int kk  = s >> 2;
        int icb = (s & 3) * 32;
        if (tid < 288) {
            int m = tid >> 2;            // 0..71: b = m&7, q = m>>3
            int g = tid & 3;
            const short* src = h2 +
                ((size_t)(b0 + (m & 7)) * NPOS + (2 * (m >> 3) + kk)) * NOC1 + icb + g * 8;
            *(short8*)&dst[m * 40 + g * 8] = *(const short8*)src;
        }
    };

    auto mfmaStep = [&](int s, const short* A) {
        short8 arow[5];
#pragma unroll
        for (int mt = 0; mt < 5; ++mt)
            arow[mt] = *(const short8*)&A[(mt * 16 + col) * 40 + rg * 8];
#pragma unroll
        for (int n = 0; n < 2; ++n) {
            size_t bo = ((size_t)((w + n * 8) * 64 + s) * 64 + lane) * 8;
            half8 Bh = __builtin_bit_cast(half8, *(const short8*)(bph + bo));
#pragma unroll
            for (int mt = 0; mt < 5; ++mt)
                acc[mt][n] = __builtin_amdgcn_mfma_f32_16x16x32_f16(
                    __builtin_bit_cast(half8, arow[mt]), Bh, acc[mt][n], 0, 0, 0);
        }
    };

    stageA(0, A0);
    __syncthreads();
    for (int s = 0; s < 64; s += 2) {
        if (s + 1 < 64) stageA(s + 1, A1);   // disjoint buffer
        mfmaStep(s, A0);
        __syncthreads();
        if (s + 2 < 64) stageA(s + 2, A0);
        mfmaStep(s + 1, A1);
        __syncthreads();
    }

    int oc2l = w * 16 + col;                  // 0..127 within half
    for (int n = 0; n < 2; ++n) {
        float bias = cb[n * 128 + oc2l];
#pragma unroll
        for (int mt = 0; mt < 5; ++mt)
#pragma unroll
            for (int r = 0; r < 4; ++r) {
                int m = mt * 16 + rg * 4 + r;
                if (m < 72)
                    p_lds[(m & 7) * 1152 + oc2l * 9 + (m >> 3)] = acc[mt][n][r] + bias;
            }
        __syncthreads();
        for (int idx = tid; idx < 1152; idx += 512) {   // 8 b x 144 caps
            int lb = idx / 144;
            int cl = idx - lb * 144;
            float* ppt = &p_lds[lb * 1152 + cl * 8];
            float sn = 0.f;
#pragma unroll
            for (int i = 0; i < NDIM; ++i) sn = fmaf(ppt[i], ppt[i], sn);
            float sc = sn / (1.f + sn) / sqrtf(sn + 1e-8f);
            float* ug = u + ((size_t)(b0 + lb) * (NCAPS * NDIM) + (n * 144 + cl) * 8);
            float4 u0 = make_float4(ppt[0] * sc, ppt[1] * sc, ppt[2] * sc, ppt[3] * sc);
            float4 u1 = make_float4(ppt[4] * sc, ppt[5] * sc, ppt[6] * sc, ppt[7] * sc);
            ((float4*)ug)[0] = u0;
            ((float4*)ug)[1] = u1;
        }
        __syncthreads();
    }
}

// ---------------- K4: u_hat + routing, 2 batches/block, 512 threads --------
// (r14 version — proven 98 µs.) Batch-pair math packed -> v_pk_fma_f32.
__global__ __launch_bounds__(512, 4) void k_routing(const float* __restrict__ u,
                                                    const float* __restrict__ Wc,
                                                    float* __restrict__ out) {
    __shared__ float b_lds[2][NCAPS * 4];     // 9216 B
    __shared__ float c_lds[2][NCAPS * 4];     // 9216 B
    __shared__ float part_lds[2][512];        // 4096 B
    __shared__ float v_lds[2][64];            // 512 B

    int tid = threadIdx.x;
    int b0  = blockIdx.x * 2;

    int g = tid >> 6;
    int l = tid & 63;
    int d = l >> 4;
    int o = l & 15;
    int gu = __builtin_amdgcn_readfirstlane(g);   // wave-uniform -> s_load for u

    const float* ub0 = u + (size_t)(b0 + 0) * (NCAPS * NDIM) + gu * 36 * NDIM;
    const float* ub1 = u + (size_t)(b0 + 1) * (NCAPS * NDIM) + gu * 36 * NDIM;

    f32x2 uh[36];
#pragma unroll
    for (int c = 0; c < 36; ++c) {
        int cap = gu * 36 + c;
        const float4* W4 = (const float4*)(Wc + ((size_t)cap * 512) + l * 8);
        float4 A  = W4[0];
        float4 Bv = W4[1];
        f32x2 u0 = {ub0[c * 8 + 0], ub1[c * 8 + 0]};
        f32x2 u1 = {ub0[c * 8 + 1], ub1[c * 8 + 1]};
        f32x2 u2 = {ub0[c * 8 + 2], ub1[c * 8 + 2]};
        f32x2 u3 = {ub0[c * 8 + 3], ub1[c * 8 + 3]};
        f32x2 u4 = {ub0[c * 8 + 4], ub1[c * 8 + 4]};
        f32x2 u5 = {ub0[c * 8 + 5], ub1[c * 8 + 5]};
        f32x2 u6 = {ub0[c * 8 + 6], ub1[c * 8 + 6]};
        f32x2 u7 = {ub0[c * 8 + 7], ub1[c * 8 + 7]};
        f32x2 t = (f32x2){A.x, A.x} * u0;
        t = pkfma(A.y,  u1, t);
        t = pkfma(A.z,  u2, t);
        t = pkfma(A.w,  u3, t);
        t = pkfma(Bv.x, u4, t);
        t = pkfma(Bv.y, u5, t);
        t = pkfma(Bv.z, u6, t);
        t = pkfma(Bv.w, u7, t);
        uh[c] = t;
    }

    for (int r = 0; r < 3; ++r) {
        if (r > 0) {
            __builtin_amdgcn_wave_barrier();
            for (int i = l; i < 72; i += 64) {
                int bb = (i >= 36) ? 1 : 0;
                int cl = i - bb * 36;
                int c  = gu * 36 + cl;
                float4 bv = *(const float4*)&b_lds[bb][c * 4];
                float m  = fmaxf(fmaxf(bv.x, bv.y), fmaxf(bv.z, bv.w));
                float e0 = expf(bv.x - m), e1 = expf(bv.y - m);
                float e2 = expf(bv.z - m), e3 = expf(bv.w - m);
                float inv = 1.f / (e0 + e1 + e2 + e3);
                e0 *= inv; e1 *= inv; e2 *= inv; e3 *= inv;
                *(float4*)&c_lds[bb][c * 4] = make_float4(e0, e1, e2, e3);
                if (r == 2) {
                    *(float4*)(out + 16384 + ((size_t)(b0 + bb) * NCAPS + c) * 4) =
                        make_float4(e0, e1, e2, e3);
                }
            }
            __builtin_amdgcn_wave_barrier();
        }

        f32x2 p = {0.f, 0.f};
        if (r == 0) {
#pragma unroll
            for (int c = 0; c < 36; ++c)
                p = pkfma(0.25f, uh[c], p);
        } else {
#pragma unroll
            for (int c = 0; c < 36; ++c) {
                f32x2 c2 = {c_lds[0][(g * 36 + c) * 4 + d],
                            c_lds[1][(g * 36 + c) * 4 + d]};
                p = c2 * uh[c] + p;    // v_pk_fma_f32
            }
        }
        part_lds[0][tid] = p.x;
        part_lds[1][tid] = p.y;
        __syncthreads();

        if (tid < 128) {
            int bb = tid >> 6;
            int ll = tid & 63;
            float sv = 0.f;
#pragma unroll
            for (int k = 0; k < 8; ++k) sv += part_lds[bb][ll + 64 * k];
            float sq = rowsum16(sv * sv);
            float sc = sq / (1.f + sq) / sqrtf(sq + 1e-8f);
            float v  = sv * sc;
            v_lds[bb][ll] = v;
            if (r == 2) {
                float vv = rowsum16(v * v);
                if ((ll & 15) == 0)
                    out[(size_t)(b0 + bb) * 4 + (ll >> 4)] = sqrtf(vv);
            }
        }
        __syncthreads();

        if (r < 2) {
            f32x2 v01 = {v_lds[0][l], v_lds[1][l]};
#pragma unroll
            for (int c = 0; c < 36; ++c) {
                f32x2 t2 = uh[c] * v01;    // packed mul
                float t0 = rowsum16(t2.x);
                float t1 = rowsum16(t2.y);
                if (o == 0) {
                    if (r == 0) {
                        b_lds[0][(g * 36 + c) * 4 + d] = t0;
                        b_lds[1][(g * 36 + c) * 4 + d] = t1;
                    } else {
                        b_lds[0][(g * 36 + c) * 4 + d] += t0;
                        b_lds[1][(g * 36 + c) * 4 + d] += t1;
                    }
                }
            }
        }
    }
}

extern "C" void kernel_launch(void* const* d_in, const int* in_sizes, int n_in,
                              void* d_out, int out_size, void* d_ws, size_t ws_size,
                              hipStream_t stream) {
    const float* x      = (const float*)d_in[0];
    const float* a      = (const float*)d_in[1];
    const float* w      = (const float*)d_in[2];
    const float* conv_w = (const float*)d_in[3];
    const float* conv_b = (const float*)d_in[4];
    const float* W_caps = (const float*)d_in[5];
    float* out = (float*)d_out;
    char* ws   = (char*)d_ws;

    short*  bwh = (short*)(ws + BWH_OFF);
    short*  bph = (short*)(ws + BPH_OFF);
    short*  h2  = (short*)(ws + H2_OFF);
    float*  u   = (float*)(ws + U_OFF);

    k_pack<<<2304, 256, 0, stream>>>(a, w, conv_w, bwh, bph);
    k_wavconv_mfma<<<BATCH / 4, 256, 0, stream>>>(x, bwh, h2);
    k_conv_mfma<<<BATCH / 8, 512, 0, stream>>>(h2, bph, conv_b, u);
    k_routing<<<BATCH / 2, 512, 0, stream>>>(u, W_caps, out);
}

// Round 17
// 238.529 us; speedup vs baseline: 1.2066x; 1.2066x over previous
//
#include <hip/hip_runtime.h>
#include <hip/hip_bf16.h>
#include <math.h>

typedef __attribute__((ext_vector_type(4))) short short4v;
typedef __attribute__((ext_vector_type(8))) short short8;
typedef __attribute__((ext_vector_type(4))) float f32x4;
typedef __attribute__((ext_vector_type(2))) float f32x2;
typedef _Float16 half8 __attribute__((ext_vector_type(8)));

#define BATCH   4096
#define XLEN    1008
#define NOC1    128
#define NPOS    32
#define NOC2    256
#define NQ      9
#define NCAPS   288
#define NDIM    8

// ws layout (bytes)
#define BWH_OFF   0           // wavelet B-pack fp16, 128 KB
#define BPH_OFF   131072      // conv2 B-pack fp16, 1 MB
#define H2_OFF    1179648     // h2 fp16 [b][pos32][ic128], 33.55 MB
#define U_OFF     34734080    // u fp32 [b][288][8], 37.75 MB

static __device__ __forceinline__ short f2h(float v) {
    _Float16 h = (_Float16)v;
    return *reinterpret_cast<short*>(&h);
}

// packed fp32 fma on batch-pairs: a (splat) * b + c  ->  v_pk_fma_f32
static __device__ __forceinline__ f32x2 pkfma(float a, f32x2 b, f32x2 c) {
    f32x2 av = {a, a};
    return av * b + c;
}

// DPP 16-lane (row) sum — VALU pipe. Bitwise == shfl_xor 1/2/4/8 tree.
template <int CTRL>
static __device__ __forceinline__ float dpp_addf(float x) {
    int y = __builtin_amdgcn_update_dpp(0, __builtin_bit_cast(int, x),
                                        CTRL, 0xf, 0xf, true);
    return x + __builtin_bit_cast(float, y);
}
static __device__ __forceinline__ float rowsum16(float x) {
    x = dpp_addf<0xB1>(x);    // quad_perm xor1
    x = dpp_addf<0x4E>(x);    // quad_perm xor2
    x = dpp_addf<0x141>(x);   // row_half_mirror
    x = dpp_addf<0x140>(x);   // row_mirror
    return x;
}

// ---------------- K1: fused weight packing (wavelet + conv2), fp16 ---------
__global__ __launch_bounds__(256) void k_pack(const float* __restrict__ a,
                                              const float* __restrict__ w,
                                              const float* __restrict__ cw,
                                              short* __restrict__ bwh,
                                              short* __restrict__ bph) {
    int bid = blockIdx.x;
    int tid = threadIdx.x;
    if (bid < 256) {
        int idx = bid * 256 + tid;            // 65536 wavelet elems
        int e    = idx & 7;
        int lane = (idx >> 3) & 63;
        int s    = (idx >> 9) & 15;
        int nt   = idx >> 13;
        int oc = nt * 16 + (lane & 15);
        int k  = s * 32 + (lane >> 4) * 8 + e;
        float t  = -1.0f + 2.0f * (float)k / 511.0f;
        float av = fmaxf(a[oc], 1e-5f);
        float ts = t / av;
        bwh[idx] = f2h(cosf(w[oc] * t) * expf(-0.5f * ts * ts));
    } else {
        int o = (bid - 256) * 256 + tid;      // 524288 conv2 elems
        int e    = o & 7;
        int lane = (o >> 3) & 63;
        int s    = (o >> 9) & 63;
        int nt   = o >> 15;
        int n  = nt * 16 + (lane & 15);
        int j  = lane >> 4;
        int kk = s >> 2;
        int ic = (s & 3) * 32 + j * 8 + e;
        bph[o] = f2h(cw[(n * NOC1 + ic) * 16 + kk]);
    }
}

// ---------------- K2: WavConv via single fp16 MFMA, occupancy-tuned --------
// Block: 4 batches, 256 threads (4 waves). launch_bounds(256,3): 170 reg
// budget (need ~130, no spill — r16's (256,4) 128-budget caused scratch
// spill: WRITE 161MB, occ 0.6%). 3 blocks/CU = 12 waves/CU latency hiding.
// Per-output K-order identical -> bit-identical h2.
__global__ __launch_bounds__(256, 3) void k_wavconv_mfma(
        const float* __restrict__ x,
        const short* __restrict__ bwh,
        short* __restrict__ h2) {
    __shared__ short xl[4][1512];   // 12096 B; slot(i) = i + 8*(i>>4)

    int tid = threadIdx.x;
    int b0  = blockIdx.x * 4;

    for (int i4 = tid; i4 < 1008; i4 += 256) {
        int b  = i4 / 252;
        int e4 = i4 - b * 252;
        float4 v = *(const float4*)(x + (size_t)(b0 + b) * XLEN + e4 * 4);
        int i    = e4 * 4;
        int slot = i + 8 * (i >> 4);
        short4v hv;
        hv.x = f2h(v.x); hv.y = f2h(v.y); hv.z = f2h(v.z); hv.w = f2h(v.w);
        *(short4v*)&xl[b][slot] = hv;
    }
    __syncthreads();

    int lane = tid & 63;
    int w    = tid >> 6;     // 0..3 == block-local batch
    int col  = lane & 15;
    int rg   = lane >> 4;    // 0..3

    f32x4 acc[2][8];
    f32x4 z = {0.f, 0.f, 0.f, 0.f};
#pragma unroll
    for (int tl = 0; tl < 2; ++tl)
#pragma unroll
        for (int nt = 0; nt < 8; ++nt) acc[tl][nt] = z;

    for (int s = 0; s < 16; ++s) {
        half8 Bh[8];
#pragma unroll
        for (int nt = 0; nt < 8; ++nt) {
            size_t off = ((size_t)(nt * 16 + s) * 64 + lane) * 8;
            Bh[nt] = __builtin_bit_cast(half8, *(const short8*)(bwh + off));
        }
#pragma unroll
        for (int tl = 0; tl < 2; ++tl) {
            int pos = tl * 16 + col;
            int i    = (pos + 2 * s) * 16 + rg * 8;
            int slot = i + 8 * (i >> 4);
            half8 ah = __builtin_bit_cast(half8, *(const short8*)&xl[w][slot]);
#pragma unroll
            for (int nt = 0; nt < 8; ++nt)
                acc[tl][nt] = __builtin_amdgcn_mfma_f32_16x16x32_f16(ah, Bh[nt], acc[tl][nt], 0, 0, 0);
        }
    }

    // Epilogue: C/D layout col=lane&15 (oc), row=rg*4+r (pos).
    int b = b0 + w;
#pragma unroll
    for (int tl = 0; tl < 2; ++tl) {
        int ph = tl * 16;
#pragma unroll
        for (int nt = 0; nt < 8; ++nt) {
            int oc = nt * 16 + col;
#pragma unroll
            for (int r = 0; r < 4; ++r) {
                int pos = ph + rg * 4 + r;
                h2[((size_t)b * NPOS + pos) * NOC1 + oc] = f2h(acc[tl][nt][r]);
            }
        }
    }
}

// ---------------- K3: PrimaryCaps conv, full-N, fp16 MFMA + squash ---------
__global__ __launch_bounds__(512, 4) void k_conv_mfma(const short* __restrict__ h2,
                                                      const short* __restrict__ bph,
                                                      const float* __restrict__ cb,
                                                      float* __restrict__ u) {
    __shared__ char smem[36864];         // 2 A-buffers (6400 B each); p_lds epilogue
    short* A0 = (short*)smem;            // [80 rows][stride 40]
    short* A1 = (short*)(smem + 6400);
    float* p_lds = (float*)smem;         // [8 b][1152]

    int tid  = threadIdx.x;
    int w    = tid >> 6;
    int lane = tid & 63;
    int col  = lane & 15;
    int rg   = lane >> 4;
    int b0   = blockIdx.x * 8;

    f32x4 acc[5][2];
    f32x4 z = {0.f, 0.f, 0.f, 0.f};
#pragma unroll
    for (int mt = 0; mt < 5; ++mt) { acc[mt][0] = z; acc[mt][1] = z; }

    auto stageA = [&](int s, short* dst) {
        int kk  = s >> 2;
        int icb = (s & 3) * 32;
        if (tid < 288) {
            int m = tid >> 2;            // 0..71: b = m&7, q = m>>3
            int g = tid & 3;
            const short* src = h2 +
                ((size_t)(b0 + (m & 7)) * NPOS + (2 * (m >> 3) + kk)) * NOC1 + icb + g * 8;
            *(short8*)&dst[m * 40 + g * 8] = *(const short8*)src;
        }
    };

    auto mfmaStep = [&](int s, const short* A) {
        short8 arow[5];
#pragma unroll
        for (int mt = 0; mt < 5; ++mt)
            arow[mt] = *(const short8*)&A[(mt * 16 + col) * 40 + rg * 8];
#pragma unroll
        for (int n = 0; n < 2; ++n) {
            size_t bo = ((size_t)((w + n * 8) * 64 + s) * 64 + lane) * 8;
            half8 Bh = __builtin_bit_cast(half8, *(const short8*)(bph + bo));
#pragma unroll
            for (int mt = 0; mt < 5; ++mt)
                acc[mt][n] = __builtin_amdgcn_mfma_f32_16x16x32_f16(
                    __builtin_bit_cast(half8, arow[mt]), Bh, acc[mt][n], 0, 0, 0);
        }
    };

    stageA(0, A0);
    __syncthreads();
    for (int s = 0; s < 64; s += 2) {
        if (s + 1 < 64) stageA(s + 1, A1);   // disjoint buffer
        mfmaStep(s, A0);
        __syncthreads();
        if (s + 2 < 64) stageA(s + 2, A0);
        mfmaStep(s + 1, A1);
        __syncthreads();
    }

    int oc2l = w * 16 + col;                  // 0..127 within half
    for (int n = 0; n < 2; ++n) {
        float bias = cb[n * 128 + oc2l];
#pragma unroll
        for (int mt = 0; mt < 5; ++mt)
#pragma unroll
            for (int r = 0; r < 4; ++r) {
                int m = mt * 16 + rg * 4 + r;
                if (m < 72)
                    p_lds[(m & 7) * 1152 + oc2l * 9 + (m >> 3)] = acc[mt][n][r] + bias;
            }
        __syncthreads();
        for (int idx = tid; idx < 1152; idx += 512) {   // 8 b x 144 caps
            int lb = idx / 144;
            int cl = idx - lb * 144;
            float* ppt = &p_lds[lb * 1152 + cl * 8];
            float sn = 0.f;
#pragma unroll
            for (int i = 0; i < NDIM; ++i) sn = fmaf(ppt[i], ppt[i], sn);
            float sc = sn / (1.f + sn) / sqrtf(sn + 1e-8f);
            float* ug = u + ((size_t)(b0 + lb) * (NCAPS * NDIM) + (n * 144 + cl) * 8);
            float4 u0 = make_float4(ppt[0] * sc, ppt[1] * sc, ppt[2] * sc, ppt[3] * sc);
            float4 u1 = make_float4(ppt[4] * sc, ppt[5] * sc, ppt[6] * sc, ppt[7] * sc);
            ((float4*)ug)[0] = u0;
            ((float4*)ug)[1] = u1;
        }
        __syncthreads();
    }
}

// ---------------- K4: u_hat + routing, 2 batches/block, 512 threads --------
// (r14 version — proven 98 µs.) Batch-pair math packed -> v_pk_fma_f32.
__global__ __launch_bounds__(512, 4) void k_routing(const float* __restrict__ u,
                                                    const float* __restrict__ Wc,
                                                    float* __restrict__ out) {
    __shared__ float b_lds[2][NCAPS * 4];     // 9216 B
    __shared__ float c_lds[2][NCAPS * 4];     // 9216 B
    __shared__ float part_lds[2][512];        // 4096 B
    __shared__ float v_lds[2][64];            // 512 B

    int tid = threadIdx.x;
    int b0  = blockIdx.x * 2;

    int g = tid >> 6;
    int l = tid & 63;
    int d = l >> 4;
    int o = l & 15;
    int gu = __builtin_amdgcn_readfirstlane(g);   // wave-uniform -> s_load for u

    const float* ub0 = u + (size_t)(b0 + 0) * (NCAPS * NDIM) + gu * 36 * NDIM;
    const float* ub1 = u + (size_t)(b0 + 1) * (NCAPS * NDIM) + gu * 36 * NDIM;

    f32x2 uh[36];
#pragma unroll
    for (int c = 0; c < 36; ++c) {
        int cap = gu * 36 + c;
        const float4* W4 = (const float4*)(Wc + ((size_t)cap * 512) + l * 8);
        float4 A  = W4[0];
        float4 Bv = W4[1];
        f32x2 u0 = {ub0[c * 8 + 0], ub1[c * 8 + 0]};
        f32x2 u1 = {ub0[c * 8 + 1], ub1[c * 8 + 1]};
        f32x2 u2 = {ub0[c * 8 + 2], ub1[c * 8 + 2]};
        f32x2 u3 = {ub0[c * 8 + 3], ub1[c * 8 + 3]};
        f32x2 u4 = {ub0[c * 8 + 4], ub1[c * 8 + 4]};
        f32x2 u5 = {ub0[c * 8 + 5], ub1[c * 8 + 5]};
        f32x2 u6 = {ub0[c * 8 + 6], ub1[c * 8 + 6]};
        f32x2 u7 = {ub0[c * 8 + 7], ub1[c * 8 + 7]};
        f32x2 t = (f32x2){A.x, A.x} * u0;
        t = pkfma(A.y,  u1, t);
        t = pkfma(A.z,  u2, t);
        t = pkfma(A.w,  u3, t);
        t = pkfma(Bv.x, u4, t);
        t = pkfma(Bv.y, u5, t);
        t = pkfma(Bv.z, u6, t);
        t = pkfma(Bv.w, u7, t);
        uh[c] = t;
    }

    for (int r = 0; r < 3; ++r) {
        if (r > 0) {
            __builtin_amdgcn_wave_barrier();
            for (int i = l; i < 72; i += 64) {
                int bb = (i >= 36) ? 1 : 0;
                int cl = i - bb * 36;
                int c  = gu * 36 + cl;
                float4 bv = *(const float4*)&b_lds[bb][c * 4];
                float m  = fmaxf(fmaxf(bv.x, bv.y), fmaxf(bv.z, bv.w));
                float e0 = expf(bv.x - m), e1 = expf(bv.y - m);
                float e2 = expf(bv.z - m), e3 = expf(bv.w - m);
                float inv = 1.f / (e0 + e1 + e2 + e3);
                e0 *= inv; e1 *= inv; e2 *= inv; e3 *= inv;
                *(float4*)&c_lds[bb][c * 4] = make_float4(e0, e1, e2, e3);
                if (r == 2) {
                    *(float4*)(out + 16384 + ((size_t)(b0 + bb) * NCAPS + c) * 4) =
                        make_float4(e0, e1, e2, e3);
                }
            }
            __builtin_amdgcn_wave_barrier();
        }

        f32x2 p = {0.f, 0.f};
        if (r == 0) {
#pragma unroll
            for (int c = 0; c < 36; ++c)
                p = pkfma(0.25f, uh[c], p);
        } else {
#pragma unroll
            for (int c = 0; c < 36; ++c) {
                f32x2 c2 = {c_lds[0][(g * 36 + c) * 4 + d],
                            c_lds[1][(g * 36 + c) * 4 + d]};
                p = c2 * uh[c] + p;    // v_pk_fma_f32
            }
        }
        part_lds[0][tid] = p.x;
        part_lds[1][tid] = p.y;
        __syncthreads();

        if (tid < 128) {
            int bb = tid >> 6;
            int ll = tid & 63;
            float sv = 0.f;
#pragma unroll
            for (int k = 0; k < 8; ++k) sv += part_lds[bb][ll + 64 * k];
            float sq = rowsum16(sv * sv);
            float sc = sq / (1.f + sq) / sqrtf(sq + 1e-8f);
            float v  = sv * sc;
            v_lds[bb][ll] = v;
            if (r == 2) {
                float vv = rowsum16(v * v);
                if ((ll & 15) == 0)
                    out[(size_t)(b0 + bb) * 4 + (ll >> 4)] = sqrtf(vv);
            }
        }
        __syncthreads();

        if (r < 2) {
            f32x2 v01 = {v_lds[0][l], v_lds[1][l]};
#pragma unroll
            for (int c = 0; c < 36; ++c) {
                f32x2 t2 = uh[c] * v01;    // packed mul
                float t0 = rowsum16(t2.x);
                float t1 = rowsum16(t2.y);
                if (o == 0) {
                    if (r == 0) {
                        b_lds[0][(g * 36 + c) * 4 + d] = t0;
                        b_lds[1][(g * 36 + c) * 4 + d] = t1;
                    } else {
                        b_lds[0][(g * 36 + c) * 4 + d] += t0;
                        b_lds[1][(g * 36 + c) * 4 + d] += t1;
                    }
                }
            }
        }
    }
}

extern "C" void kernel_launch(void* const* d_in, const int* in_sizes, int n_in,
                              void* d_out, int out_size, void* d_ws, size_t ws_size,
                              hipStream_t stream) {
    const float* x      = (const float*)d_in[0];
    const float* a      = (const float*)d_in[1];
    const float* w      = (const float*)d_in[2];
    const float* conv_w = (const float*)d_in[3];
    const float* conv_b = (const float*)d_in[4];
    const float* W_caps = (const float*)d_in[5];
    float* out = (float*)d_out;
    char* ws   = (char*)d_ws;

    short*  bwh = (short*)(ws + BWH_OFF);
    short*  bph = (short*)(ws + BPH_OFF);
    short*  h2  = (short*)(ws + H2_OFF);
    float*  u   = (float*)(ws + U_OFF);

    k_pack<<<2304, 256, 0, stream>>>(a, w, conv_w, bwh, bph);
    k_wavconv_mfma<<<BATCH / 4, 256, 0, stream>>>(x, bwh, h2);
    k_conv_mfma<<<BATCH / 8, 512, 0, stream>>>(h2, bph, conv_b, u);
    k_routing<<<BATCH / 2, 512, 0, stream>>>(u, W_caps, out);
}